// Round 11
// baseline (29.487 us; speedup 1.0000x reference)
//
#include <hip/hip_runtime.h>

#define NUM_SAMPLES 64
#define HIDDEN 64
#define Z_NEAR 2.0f
#define Z_FAR 6.0f
#define LOG2E 1.44269504088896f

typedef _Float16 half8 __attribute__((ext_vector_type(8)));
typedef __fp16  fp16x2 __attribute__((ext_vector_type(2)));
typedef float   float4t __attribute__((ext_vector_type(4)));

// 6-step wave64 inclusive add-scan, pure VALU (DPP), zero LDS traffic.
template<int CTRL, int RMASK>
__device__ __forceinline__ float dpp_add(float x) {
    const int m = __builtin_amdgcn_update_dpp(0, __float_as_int(x), CTRL, RMASK, 0xf, true);
    return x + __int_as_float(m);
}
__device__ __forceinline__ float wave_scan_add(float x) {
    x = dpp_add<0x111, 0xf>(x);   // row_shr:1
    x = dpp_add<0x112, 0xf>(x);   // row_shr:2
    x = dpp_add<0x114, 0xf>(x);   // row_shr:4
    x = dpp_add<0x118, 0xf>(x);   // row_shr:8
    x = dpp_add<0x142, 0xa>(x);   // row_bcast:15 -> rows 1,3
    x = dpp_add<0x143, 0xc>(x);   // row_bcast:31 -> rows 2,3
    return x;                     // lane63 = full sum
}

// 16B-slot swizzle for C redistribution: <=2-way banks (free).
__device__ __forceinline__ int slot16(int s) { return 2*s + ((s>>2)&1); }

// R9 structure (28.2us, verified), textually zipped x2 rays per wave.
// All per-ray state is scalar A/B-suffixed; each ray has its own LDS arrays
// (no [2] indexing anywhere). Per-ray math byte-for-byte R9. No barriers.
__global__ __launch_bounds__(256) void render_kernel(
    const float* __restrict__ cam,    // 4x4
    const float* __restrict__ u,      // R x S
    const float* __restrict__ cdirs,  // R x 3
    const float* __restrict__ W1,     // 6 x 64
    const float* __restrict__ b1,     // 64
    const float* __restrict__ W2,     // 64 x 4
    const float* __restrict__ b2,     // 4
    float* __restrict__ out)          // R x 3
{
    const int lane = threadIdx.x & 63;
    const int wid  = threadIdx.x >> 6;
    const int grp  = lane >> 4;       // k-group
    const int col  = lane & 15;       // sample-in-tile
    const int rayA = blockIdx.x * 8 + wid * 2;
    const int rayB = rayA + 1;

    __shared__ __align__(16) __fp16 AhshA[4][HIDDEN];
    __shared__ __align__(16) __fp16 BhshA[4][HIDDEN];
    __shared__ __align__(16) __fp16 AhshB[4][HIDDEN];
    __shared__ __align__(16) __fp16 BhshB[4][HIDDEN];
    __shared__ __align__(16) float  tshA[4][NUM_SAMPLES];
    __shared__ __align__(16) float  tshB[4][NUM_SAMPLES];
    __shared__ __align__(16) __fp16 W2T[4][4][80];          // fp16 W2^T (ray-invariant)
    __shared__ __align__(16) float  cstA[4][NUM_SAMPLES*8]; // 16B slots, swizzled
    __shared__ __align__(16) float  cstB[4][NUM_SAMPLES*8];

    // per-wave fp16 W2^T staging (lane = hidden unit h)
    {
        const float4 w2row = ((const float4*)W2)[lane];
        W2T[wid][0][lane] = (__fp16)w2row.x;
        W2T[wid][1][lane] = (__fp16)w2row.y;
        W2T[wid][2][lane] = (__fp16)w2row.z;
        W2T[wid][3][lane] = (__fp16)w2row.w;
    }

    // both rays' u and cdirs loads issued first (overlap their latency)
    const float uvA = u[rayA*NUM_SAMPLES + lane];            // coalesced
    const float uvB = u[rayB*NUM_SAMPLES + lane];
    const float cdA0 = cdirs[rayA*3+0], cdA1 = cdirs[rayA*3+1], cdA2 = cdirs[rayA*3+2];
    const float cdB0 = cdirs[rayB*3+0], cdB1 = cdirs[rayB*3+1], cdB2 = cdirs[rayB*3+2];

    // ray-invariant weights
    const float w10 = W1[0*HIDDEN+lane], w11 = W1[1*HIDDEN+lane], w12 = W1[2*HIDDEN+lane];
    const float w13 = W1[3*HIDDEN+lane], w14 = W1[4*HIDDEN+lane], w15 = W1[5*HIDDEN+lane];
    const float b1h = b1[lane];
    const float b20 = b2[0], b21 = b2[1], b22 = b2[2], b23 = b2[3];
    const float o0 = cam[3], o1 = cam[7], o2 = cam[11];

    // ray dirs
    const float rdA0 = fmaf(cam[0], cdA0, fmaf(cam[1], cdA1, cam[2]*cdA2));
    const float rdA1 = fmaf(cam[4], cdA0, fmaf(cam[5], cdA1, cam[6]*cdA2));
    const float rdA2 = fmaf(cam[8], cdA0, fmaf(cam[9], cdA1, cam[10]*cdA2));
    const float rdB0 = fmaf(cam[0], cdB0, fmaf(cam[1], cdB1, cam[2]*cdB2));
    const float rdB1 = fmaf(cam[4], cdB0, fmaf(cam[5], cdB1, cam[6]*cdB2));
    const float rdB2 = fmaf(cam[8], cdB0, fmaf(cam[9], cdB1, cam[10]*cdB2));

    // per-hidden-unit affine coeffs (h = lane), staged f16
    {
        const float AA = fmaf(rdA0, w10, fmaf(rdA1, w11, rdA2*w12));
        float BA = fmaf(o0, w10, fmaf(o1, w11, o2*w12));
        BA = fmaf(rdA0, w13, fmaf(rdA1, w14, fmaf(rdA2, w15, BA))) + b1h;
        AhshA[wid][lane] = (__fp16)AA;
        BhshA[wid][lane] = (__fp16)BA;
        const float AB = fmaf(rdB0, w10, fmaf(rdB1, w11, rdB2*w12));
        float BB = fmaf(o0, w10, fmaf(o1, w11, o2*w12));
        BB = fmaf(rdB0, w13, fmaf(rdB1, w14, fmaf(rdB2, w15, BB))) + b1h;
        AhshB[wid][lane] = (__fp16)AB;
        BhshB[wid][lane] = (__fp16)BB;
    }

    const float bin_dt = (Z_FAR - Z_NEAR) / (float)NUM_SAMPLES;
    const float tA = fmaf((float)lane + uvA, bin_dt, Z_NEAR);
    const float tB = fmaf((float)lane + uvB, bin_dt, Z_NEAR);
    tshA[wid][lane] = tA;
    tshB[wid][lane] = tB;

    // hoisted fp16 coefficient pairs: h = kt*32 + grp*8 + 2q
    union u8 { fp16x2 h2[4]; half8 h8; };
    u8 aAhA[2], aBhA[2], aAhB[2], aBhB[2];
    #pragma unroll
    for (int kt = 0; kt < 2; ++kt) {
        const int h0 = kt*32 + grp*8;
        aAhA[kt].h8 = *(const half8*)(&AhshA[wid][h0]);
        aBhA[kt].h8 = *(const half8*)(&BhshA[wid][h0]);
        aAhB[kt].h8 = *(const half8*)(&AhshB[wid][h0]);
        aBhB[kt].h8 = *(const half8*)(&BhshB[wid][h0]);
    }

    // W-fragment (A-operand of swapped MFMA): W2T rows, zero for col>=4
    half8 bfrag[2] = {};
    if (col < 4) {
        bfrag[0] = *(const half8*)(&W2T[wid][col][grp*8]);
        bfrag[1] = *(const half8*)(&W2T[wid][col][32 + grp*8]);
    }

    // sep from neighbor t
    const float tnA  = tshA[wid][(lane+1) & 63];
    const float sepA = (lane < NUM_SAMPLES-1) ? (tnA - tA) : bin_dt;
    const float tnB  = tshB[wid][(lane+1) & 63];
    const float sepB = (lane < NUM_SAMPLES-1) ? (tnB - tB) : bin_dt;

    const fp16x2 hzero = {(__fp16)0.0f, (__fp16)0.0f};

    // 4 M-tiles; both rays zipped per tile; swapped MFMA -> lanes 0-15 hold
    // outputs 0-3 of sample 16m+col -> one b128 write per ray per tile.
    #pragma unroll
    for (int m = 0; m < 4; ++m) {
        const float tmA = tshA[wid][col + 16*m];
        const float tmB = tshB[wid][col + 16*m];
        const fp16x2 tvhA = __builtin_amdgcn_cvt_pkrtz(tmA, tmA);
        const fp16x2 tvhB = __builtin_amdgcn_cvt_pkrtz(tmB, tmB);
        float4t cA = {0.f, 0.f, 0.f, 0.f};
        float4t cB = {0.f, 0.f, 0.f, 0.f};
        #pragma unroll
        for (int kt = 0; kt < 2; ++kt) {
            u8 auA, auB;
            #pragma unroll
            for (int q = 0; q < 4; ++q) {
                const fp16x2 preA = __builtin_elementwise_fma(aAhA[kt].h2[q], tvhA, aBhA[kt].h2[q]);
                auA.h2[q] = __builtin_elementwise_max(preA, hzero);
                const fp16x2 preB = __builtin_elementwise_fma(aAhB[kt].h2[q], tvhB, aBhB[kt].h2[q]);
                auB.h2[q] = __builtin_elementwise_max(preB, hzero);
            }
            cA = __builtin_amdgcn_mfma_f32_16x16x32_f16(bfrag[kt], auA.h8, cA, 0, 0, 0);
            cB = __builtin_amdgcn_mfma_f32_16x16x32_f16(bfrag[kt], auB.h8, cB, 0, 0, 0);
        }
        if (lane < 16) {
            *(float4t*)(&cstA[wid][slot16(16*m + lane) * 4]) = cA;
            *(float4t*)(&cstB[wid][slot16(16*m + lane) * 4]) = cB;
        }
    }

    // readback + composite, both rays zipped
    const float4t c4A = *(const float4t*)(&cstA[wid][slot16(lane) * 4]);
    const float4t c4B = *(const float4t*)(&cstB[wid][slot16(lane) * 4]);

    const float accA0 = c4A[0] + b20, accA1 = c4A[1] + b21;
    const float accA2 = c4A[2] + b22, accA3 = c4A[3] + b23;
    const float accB0 = c4B[0] + b20, accB1 = c4B[1] + b21;
    const float accB2 = c4B[2] + b22, accB3 = c4B[3] + b23;

    const float dsepA  = fmaxf(accA0, 0.0f) * sepA;
    const float dsepB  = fmaxf(accB0, 0.0f) * sepB;
    const float lgA    = -dsepA * LOG2E;
    const float lgB    = -dsepB * LOG2E;
    const float alphaA = 1.0f - __builtin_amdgcn_exp2f(lgA);
    const float alphaB = 1.0f - __builtin_amdgcn_exp2f(lgB);
    const float SA     = wave_scan_add(lgA);
    const float SB     = wave_scan_add(lgB);
    const float TA     = __builtin_amdgcn_exp2f(SA - lgA);
    const float TB     = __builtin_amdgcn_exp2f(SB - lgB);
    const float wA     = alphaA * TA;
    const float wB     = alphaB * TB;

    float cA0 = wA * __builtin_amdgcn_rcpf(1.0f + __builtin_amdgcn_exp2f(-accA1 * LOG2E));
    float cA1 = wA * __builtin_amdgcn_rcpf(1.0f + __builtin_amdgcn_exp2f(-accA2 * LOG2E));
    float cA2 = wA * __builtin_amdgcn_rcpf(1.0f + __builtin_amdgcn_exp2f(-accA3 * LOG2E));
    float cB0 = wB * __builtin_amdgcn_rcpf(1.0f + __builtin_amdgcn_exp2f(-accB1 * LOG2E));
    float cB1 = wB * __builtin_amdgcn_rcpf(1.0f + __builtin_amdgcn_exp2f(-accB2 * LOG2E));
    float cB2 = wB * __builtin_amdgcn_rcpf(1.0f + __builtin_amdgcn_exp2f(-accB3 * LOG2E));
    cA0 = wave_scan_add(cA0);
    cA1 = wave_scan_add(cA1);
    cA2 = wave_scan_add(cA2);
    cB0 = wave_scan_add(cB0);
    cB1 = wave_scan_add(cB1);
    cB2 = wave_scan_add(cB2);

    if (lane == 63) {
        out[rayA*3+0] = cA0;
        out[rayA*3+1] = cA1;
        out[rayA*3+2] = cA2;
        out[rayB*3+0] = cB0;
        out[rayB*3+1] = cB1;
        out[rayB*3+2] = cB2;
    }
}

extern "C" void kernel_launch(void* const* d_in, const int* in_sizes, int n_in,
                              void* d_out, int out_size, void* d_ws, size_t ws_size,
                              hipStream_t stream) {
    const float* cam   = (const float*)d_in[0];
    const float* u     = (const float*)d_in[1];
    const float* cdirs = (const float*)d_in[2];
    const float* W1    = (const float*)d_in[3];
    const float* b1    = (const float*)d_in[4];
    const float* W2    = (const float*)d_in[5];
    const float* b2    = (const float*)d_in[6];
    float* out = (float*)d_out;

    const int R = 256 * 256;
    dim3 grid(R / 8), block(256);   // 4 waves x 2 rays per block
    render_kernel<<<grid, block, 0, stream>>>(cam, u, cdirs, W1, b1, W2, b2, out);
}

// Round 12
// 29.019 us; speedup vs baseline: 1.0161x; 1.0161x over previous
//
#include <hip/hip_runtime.h>

#define NUM_SAMPLES 64
#define HIDDEN 64
#define Z_NEAR 2.0f
#define Z_FAR 6.0f
#define LOG2E 1.44269504088896f

typedef _Float16 half8 __attribute__((ext_vector_type(8)));
typedef __fp16  fp16x2 __attribute__((ext_vector_type(2)));
typedef float   float4t __attribute__((ext_vector_type(4)));

// 6-step wave64 inclusive add-scan, pure VALU (DPP), zero LDS traffic.
template<int CTRL, int RMASK>
__device__ __forceinline__ float dpp_add(float x) {
    const int m = __builtin_amdgcn_update_dpp(0, __float_as_int(x), CTRL, RMASK, 0xf, true);
    return x + __int_as_float(m);
}
__device__ __forceinline__ float wave_scan_add(float x) {
    x = dpp_add<0x111, 0xf>(x);   // row_shr:1
    x = dpp_add<0x112, 0xf>(x);   // row_shr:2
    x = dpp_add<0x114, 0xf>(x);   // row_shr:4
    x = dpp_add<0x118, 0xf>(x);   // row_shr:8
    x = dpp_add<0x142, 0xa>(x);   // row_bcast:15 -> rows 1,3
    x = dpp_add<0x143, 0xc>(x);   // row_bcast:31 -> rows 2,3
    return x;                     // lane63 = full sum
}

// 16B-slot swizzle for C redistribution: <=2-way banks (free).
__device__ __forceinline__ int slot16(int s) { return 2*s + ((s>>2)&1); }

// R9 structure (28.2us, verified); 2 SEQUENTIAL rays per wave:
// - both rays' global loads issued at wave start (ray B latency hides under A)
// - W2T/bfrag/W1/b1 setup amortized over 2 rays
// - tsh deleted: t/tn/tm recomputed from u loads (VMEM broadcast, L1-warm)
// - compute phases serialized (peak VGPR stays low -> 8 waves/SIMD)
// Per-ray math identical to R9. No barriers.
__global__ __launch_bounds__(256) void render_kernel(
    const float* __restrict__ cam,    // 4x4
    const float* __restrict__ u,      // R x S
    const float* __restrict__ cdirs,  // R x 3
    const float* __restrict__ W1,     // 6 x 64
    const float* __restrict__ b1,     // 64
    const float* __restrict__ W2,     // 64 x 4
    const float* __restrict__ b2,     // 4
    float* __restrict__ out)          // R x 3
{
    const int lane = threadIdx.x & 63;
    const int wid  = threadIdx.x >> 6;
    const int grp  = lane >> 4;       // k-group
    const int col  = lane & 15;       // sample-in-tile
    const int rayA = blockIdx.x * 8 + wid * 2;
    const int rayB = rayA + 1;

    __shared__ __align__(16) __fp16 AhshA[4][HIDDEN];
    __shared__ __align__(16) __fp16 BhshA[4][HIDDEN];
    __shared__ __align__(16) __fp16 AhshB[4][HIDDEN];
    __shared__ __align__(16) __fp16 BhshB[4][HIDDEN];
    __shared__ __align__(16) __fp16 W2T[4][4][80];          // fp16 W2^T (ray-invariant)
    __shared__ __align__(16) float  cst[4][NUM_SAMPLES*8];  // 16B slots, swizzled; reused A->B

    // per-wave fp16 W2^T staging (lane = hidden unit h)
    {
        const float4 w2row = ((const float4*)W2)[lane];
        W2T[wid][0][lane] = (__fp16)w2row.x;
        W2T[wid][1][lane] = (__fp16)w2row.y;
        W2T[wid][2][lane] = (__fp16)w2row.z;
        W2T[wid][3][lane] = (__fp16)w2row.w;
    }

    // ---- ALL global loads for both rays issued up front ----
    const float* upA = u + rayA*NUM_SAMPLES;
    const float* upB = u + rayB*NUM_SAMPLES;
    const int lnext = (lane < 63) ? lane+1 : 63;            // clamp (lane63 sep unused)
    const float uvA  = upA[lane];
    const float uvAn = upA[lnext];
    const float uA0 = upA[col], uA1 = upA[16+col], uA2 = upA[32+col], uA3 = upA[48+col];
    const float uvB  = upB[lane];
    const float uvBn = upB[lnext];
    const float uB0 = upB[col], uB1 = upB[16+col], uB2 = upB[32+col], uB3 = upB[48+col];

    // cdirs: wave-uniform scalar loads
    const float cdA0 = cdirs[rayA*3+0], cdA1 = cdirs[rayA*3+1], cdA2 = cdirs[rayA*3+2];
    const float cdB0 = cdirs[rayB*3+0], cdB1 = cdirs[rayB*3+1], cdB2 = cdirs[rayB*3+2];

    // ray-invariant weights
    const float w10 = W1[0*HIDDEN+lane], w11 = W1[1*HIDDEN+lane], w12 = W1[2*HIDDEN+lane];
    const float w13 = W1[3*HIDDEN+lane], w14 = W1[4*HIDDEN+lane], w15 = W1[5*HIDDEN+lane];
    const float b1h = b1[lane];
    const float b20 = b2[0], b21 = b2[1], b22 = b2[2], b23 = b2[3];
    const float o0 = cam[3], o1 = cam[7], o2 = cam[11];

    // ---- both rays' affine coeffs computed+staged up front ----
    {
        const float rdA0 = fmaf(cam[0], cdA0, fmaf(cam[1], cdA1, cam[2]*cdA2));
        const float rdA1 = fmaf(cam[4], cdA0, fmaf(cam[5], cdA1, cam[6]*cdA2));
        const float rdA2 = fmaf(cam[8], cdA0, fmaf(cam[9], cdA1, cam[10]*cdA2));
        const float AA = fmaf(rdA0, w10, fmaf(rdA1, w11, rdA2*w12));
        float BA = fmaf(o0, w10, fmaf(o1, w11, o2*w12));
        BA = fmaf(rdA0, w13, fmaf(rdA1, w14, fmaf(rdA2, w15, BA))) + b1h;
        AhshA[wid][lane] = (__fp16)AA;
        BhshA[wid][lane] = (__fp16)BA;

        const float rdB0 = fmaf(cam[0], cdB0, fmaf(cam[1], cdB1, cam[2]*cdB2));
        const float rdB1 = fmaf(cam[4], cdB0, fmaf(cam[5], cdB1, cam[6]*cdB2));
        const float rdB2 = fmaf(cam[8], cdB0, fmaf(cam[9], cdB1, cam[10]*cdB2));
        const float AB = fmaf(rdB0, w10, fmaf(rdB1, w11, rdB2*w12));
        float BB = fmaf(o0, w10, fmaf(o1, w11, o2*w12));
        BB = fmaf(rdB0, w13, fmaf(rdB1, w14, fmaf(rdB2, w15, BB))) + b1h;
        AhshB[wid][lane] = (__fp16)AB;
        BhshB[wid][lane] = (__fp16)BB;
    }

    // W-fragment (A-operand of swapped MFMA): W2T rows, zero for col>=4
    half8 bfrag[2] = {};
    if (col < 4) {
        bfrag[0] = *(const half8*)(&W2T[wid][col][grp*8]);
        bfrag[1] = *(const half8*)(&W2T[wid][col][32 + grp*8]);
    }

    const float bin_dt = (Z_FAR - Z_NEAR) / (float)NUM_SAMPLES;
    const fp16x2 hzero = {(__fp16)0.0f, (__fp16)0.0f};
    union u8t { fp16x2 h2[4]; half8 h8; };

    float resA0, resA1, resA2, resB0, resB1, resB2;

    // ================= RAY A =================
    {
        u8t aAh[2], aBh[2];
        #pragma unroll
        for (int kt = 0; kt < 2; ++kt) {
            const int h0 = kt*32 + grp*8;
            aAh[kt].h8 = *(const half8*)(&AhshA[wid][h0]);
            aBh[kt].h8 = *(const half8*)(&BhshA[wid][h0]);
        }
        const float t   = fmaf((float)lane + uvA, bin_dt, Z_NEAR);
        const float tn  = fmaf((float)(lane+1) + uvAn, bin_dt, Z_NEAR);
        const float sep = (lane < NUM_SAMPLES-1) ? (tn - t) : bin_dt;

        #pragma unroll
        for (int m = 0; m < 4; ++m) {
            const float um = (m==0) ? uA0 : (m==1) ? uA1 : (m==2) ? uA2 : uA3;
            const float tm = fmaf((float)(16*m + col) + um, bin_dt, Z_NEAR);
            const fp16x2 tvh = __builtin_amdgcn_cvt_pkrtz(tm, tm);
            float4t c = {0.f, 0.f, 0.f, 0.f};
            #pragma unroll
            for (int kt = 0; kt < 2; ++kt) {
                u8t au;
                #pragma unroll
                for (int q = 0; q < 4; ++q) {
                    const fp16x2 pre = __builtin_elementwise_fma(aAh[kt].h2[q], tvh, aBh[kt].h2[q]);
                    au.h2[q] = __builtin_elementwise_max(pre, hzero);
                }
                c = __builtin_amdgcn_mfma_f32_16x16x32_f16(bfrag[kt], au.h8, c, 0, 0, 0);
            }
            if (lane < 16)
                *(float4t*)(&cst[wid][slot16(16*m + lane) * 4]) = c;
        }

        const float4t c4 = *(const float4t*)(&cst[wid][slot16(lane) * 4]);
        const float acc0 = c4[0] + b20, acc1 = c4[1] + b21;
        const float acc2 = c4[2] + b22, acc3 = c4[3] + b23;

        const float dsep  = fmaxf(acc0, 0.0f) * sep;
        const float lg    = -dsep * LOG2E;
        const float alpha = 1.0f - __builtin_amdgcn_exp2f(lg);
        const float S     = wave_scan_add(lg);
        const float T     = __builtin_amdgcn_exp2f(S - lg);
        const float w     = alpha * T;

        float c0 = w * __builtin_amdgcn_rcpf(1.0f + __builtin_amdgcn_exp2f(-acc1 * LOG2E));
        float c1 = w * __builtin_amdgcn_rcpf(1.0f + __builtin_amdgcn_exp2f(-acc2 * LOG2E));
        float c2 = w * __builtin_amdgcn_rcpf(1.0f + __builtin_amdgcn_exp2f(-acc3 * LOG2E));
        resA0 = wave_scan_add(c0);
        resA1 = wave_scan_add(c1);
        resA2 = wave_scan_add(c2);
    }

    // ================= RAY B =================
    {
        u8t aAh[2], aBh[2];
        #pragma unroll
        for (int kt = 0; kt < 2; ++kt) {
            const int h0 = kt*32 + grp*8;
            aAh[kt].h8 = *(const half8*)(&AhshB[wid][h0]);
            aBh[kt].h8 = *(const half8*)(&BhshB[wid][h0]);
        }
        const float t   = fmaf((float)lane + uvB, bin_dt, Z_NEAR);
        const float tn  = fmaf((float)(lane+1) + uvBn, bin_dt, Z_NEAR);
        const float sep = (lane < NUM_SAMPLES-1) ? (tn - t) : bin_dt;

        #pragma unroll
        for (int m = 0; m < 4; ++m) {
            const float um = (m==0) ? uB0 : (m==1) ? uB1 : (m==2) ? uB2 : uB3;
            const float tm = fmaf((float)(16*m + col) + um, bin_dt, Z_NEAR);
            const fp16x2 tvh = __builtin_amdgcn_cvt_pkrtz(tm, tm);
            float4t c = {0.f, 0.f, 0.f, 0.f};
            #pragma unroll
            for (int kt = 0; kt < 2; ++kt) {
                u8t au;
                #pragma unroll
                for (int q = 0; q < 4; ++q) {
                    const fp16x2 pre = __builtin_elementwise_fma(aAh[kt].h2[q], tvh, aBh[kt].h2[q]);
                    au.h2[q] = __builtin_elementwise_max(pre, hzero);
                }
                c = __builtin_amdgcn_mfma_f32_16x16x32_f16(bfrag[kt], au.h8, c, 0, 0, 0);
            }
            if (lane < 16)
                *(float4t*)(&cst[wid][slot16(16*m + lane) * 4]) = c;
        }

        const float4t c4 = *(const float4t*)(&cst[wid][slot16(lane) * 4]);
        const float acc0 = c4[0] + b20, acc1 = c4[1] + b21;
        const float acc2 = c4[2] + b22, acc3 = c4[3] + b23;

        const float dsep  = fmaxf(acc0, 0.0f) * sep;
        const float lg    = -dsep * LOG2E;
        const float alpha = 1.0f - __builtin_amdgcn_exp2f(lg);
        const float S     = wave_scan_add(lg);
        const float T     = __builtin_amdgcn_exp2f(S - lg);
        const float w     = alpha * T;

        float c0 = w * __builtin_amdgcn_rcpf(1.0f + __builtin_amdgcn_exp2f(-acc1 * LOG2E));
        float c1 = w * __builtin_amdgcn_rcpf(1.0f + __builtin_amdgcn_exp2f(-acc2 * LOG2E));
        float c2 = w * __builtin_amdgcn_rcpf(1.0f + __builtin_amdgcn_exp2f(-acc3 * LOG2E));
        resB0 = wave_scan_add(c0);
        resB1 = wave_scan_add(c1);
        resB2 = wave_scan_add(c2);
    }

    if (lane == 63) {
        out[rayA*3+0] = resA0;
        out[rayA*3+1] = resA1;
        out[rayA*3+2] = resA2;
        out[rayB*3+0] = resB0;
        out[rayB*3+1] = resB1;
        out[rayB*3+2] = resB2;
    }
}

extern "C" void kernel_launch(void* const* d_in, const int* in_sizes, int n_in,
                              void* d_out, int out_size, void* d_ws, size_t ws_size,
                              hipStream_t stream) {
    const float* cam   = (const float*)d_in[0];
    const float* u     = (const float*)d_in[1];
    const float* cdirs = (const float*)d_in[2];
    const float* W1    = (const float*)d_in[3];
    const float* b1    = (const float*)d_in[4];
    const float* W2    = (const float*)d_in[5];
    const float* b2    = (const float*)d_in[6];
    float* out = (float*)d_out;

    const int R = 256 * 256;
    dim3 grid(R / 8), block(256);   // 4 waves x 2 sequential rays per block
    render_kernel<<<grid, block, 0, stream>>>(cam, u, cdirs, W1, b1, W2, b2, out);
}